// Round 5
// baseline (604.872 us; speedup 1.0000x reference)
//
#include <hip/hip_runtime.h>

typedef unsigned short u16;
typedef unsigned int   u32;
typedef _Float16 half2_t __attribute__((ext_vector_type(2)));
typedef _Float16 f16x8  __attribute__((ext_vector_type(8)));
typedef float    f32x16 __attribute__((ext_vector_type(16)));
typedef float    f32x4  __attribute__((ext_vector_type(4)));
typedef unsigned u32x4  __attribute__((ext_vector_type(4)));
typedef unsigned u32x2  __attribute__((ext_vector_type(2)));

// packed-weight layout (u32 word indices within pw region)
#define W1T_OFF   0        // [t][mt][kc][lane][4] MFMA A-frags of W1^T (f16 pairs)
#define W2T_OFF   4096
#define B1F_OFF   8192     // [t][mt][lane] bias A-frag word
#define B2F_OFF   8448
#define NWO1_OFF  8704     // node MLP: [48][64] f16-pairs over k
#define NWO2_OFF  11776    // [32][64]
#define NWO3_OFF  13824    // [32][32]
#define NB_OFF    14848    // floats: bo1[64] bo2[64] bo3[32]
#define PW_WORDS  15008

__device__ __forceinline__ u16 f2h_bits(float f){ _Float16 h=(_Float16)f; return __builtin_bit_cast(u16,h); }
__device__ __forceinline__ half2_t h2u(u32 u){ return __builtin_bit_cast(half2_t,u); }

__device__ __forceinline__ u32 pkrtz(float a, float b){
#if defined(__has_builtin)
#if __has_builtin(__builtin_amdgcn_cvt_pkrtz)
  auto r = __builtin_amdgcn_cvt_pkrtz(a,b);
  return __builtin_bit_cast(u32, r);
#else
  return (u32)f2h_bits(a) | ((u32)f2h_bits(b)<<16);
#endif
#else
  return (u32)f2h_bits(a) | ((u32)f2h_bits(b)<<16);
#endif
}

// permlane32_swap: out0 = {a.lo32, b.lo32}, out1 = {a.hi32, b.hi32}
__device__ __forceinline__ u32x2 plswap(u32 a, u32 b){
#if defined(__has_builtin)
#if __has_builtin(__builtin_amdgcn_permlane32_swap)
  return __builtin_amdgcn_permlane32_swap(a, b, false, false);
#else
  u32 pa = (u32)__shfl_xor((int)a, 32);
  u32 pb = (u32)__shfl_xor((int)b, 32);
  int hh = (int)((threadIdx.x & 63) >> 5);
  u32x2 r; r[0] = hh ? pb : a; r[1] = hh ? b : pa; return r;
#endif
#else
  u32 pa = (u32)__shfl_xor((int)a, 32);
  u32 pb = (u32)__shfl_xor((int)b, 32);
  int hh = (int)((threadIdx.x & 63) >> 5);
  u32x2 r; r[0] = hh ? pb : a; r[1] = hh ? b : pa; return r;
#endif
}

#define MFMA(A,B,C) __builtin_amdgcn_mfma_f32_32x32x16_f16((A),(B),(C),0,0,0)

#if defined(__has_builtin)
#if __has_builtin(__builtin_amdgcn_fdot2)
#define FDOT2(a,b,c) __builtin_amdgcn_fdot2((a),(b),(c),false)
#endif
#endif
#ifndef FDOT2
#define FDOT2(a,b,c) (fmaf((float)(a)[1],(float)(b)[1], fmaf((float)(a)[0],(float)(b)[0],(c))))
#endif

// ---------------- prep: pack weights into MFMA frag / dot2 layouts ------------------
__global__ void prep_kernel(const float* __restrict__ W1, const float* __restrict__ b1,
                            const float* __restrict__ W2, const float* __restrict__ b2,
                            const float* __restrict__ Wo1, const float* __restrict__ bo1,
                            const float* __restrict__ Wo2, const float* __restrict__ bo2,
                            const float* __restrict__ Wo3, const float* __restrict__ bo3,
                            u32* __restrict__ pw)
{
  int i = blockIdx.x*blockDim.x + threadIdx.x;
  for (; i < PW_WORDS; i += gridDim.x*blockDim.x) {
    if (i < 4096) {                         // W1^T A-frags
      int r=i&3, lane=(i>>2)&63, kc=(i>>8)&3, mt=(i>>10)&1, t=(i>>11)&1;
      int h=lane>>5, feat=mt*32+(lane&31);
      int k0=kc*16 + h*8 + 2*r;
      float lo=W1[t*4096 + k0*64 + feat], hi=W1[t*4096 + (k0+1)*64 + feat];
      pw[W1T_OFF+i] = (u32)f2h_bits(lo) | ((u32)f2h_bits(hi)<<16);
    } else if (i < 8192) {                  // W2^T A-frags
      int q=i-4096;
      int r=q&3, lane=(q>>2)&63, kc=(q>>8)&3, mt=(q>>10)&1, t=(q>>11)&1;
      int h=lane>>5, feat=mt*32+(lane&31);
      int k0=kc*16 + h*8 + 2*r;
      float lo=W2[t*4096 + k0*64 + feat], hi=W2[t*4096 + (k0+1)*64 + feat];
      pw[i] = (u32)f2h_bits(lo) | ((u32)f2h_bits(hi)<<16);
    } else if (i < 8448) {                  // b1 bias frag word
      int q=i-8192; int lane=q&63, mt=(q>>6)&1, t=(q>>7)&1;
      pw[i] = (lane<32) ? (u32)f2h_bits(b1[t*64 + mt*32 + (lane&31)]) : 0u;
    } else if (i < 8704) {                  // b2 bias frag word
      int q=i-8448; int lane=q&63, mt=(q>>6)&1, t=(q>>7)&1;
      pw[i] = (lane<32) ? (u32)f2h_bits(b2[t*64 + mt*32 + (lane&31)]) : 0u;
    } else if (i < 11776) {                 // node Wo1 [48 kk][64 j]
      int q=i-NWO1_OFF, kk=q>>6, j=q&63;
      pw[i] = (u32)f2h_bits(Wo1[(2*kk)*64 + j]) | ((u32)f2h_bits(Wo1[(2*kk+1)*64 + j])<<16);
    } else if (i < 13824) {                 // node Wo2 [32][64]
      int q=i-NWO2_OFF, kk=q>>6, j=q&63;
      pw[i] = (u32)f2h_bits(Wo2[(2*kk)*64 + j]) | ((u32)f2h_bits(Wo2[(2*kk+1)*64 + j])<<16);
    } else if (i < 14848) {                 // node Wo3 [32][32]
      int q=i-NWO3_OFF, kk=q>>5, j=q&31;
      pw[i] = (u32)f2h_bits(Wo3[(2*kk)*32 + j]) | ((u32)f2h_bits(Wo3[(2*kk+1)*32 + j])<<16);
    } else {                                // node biases f32
      int q = i - NB_OFF;
      float* nb = (float*)(pw + NB_OFF);
      float v;
      if (q < 64)       v = bo1[q];
      else if (q < 128) v = bo2[q-64];
      else              v = bo3[q-128];
      nb[q] = v;
    }
  }
}

// ---------------- CSR build: histogram -> scan -> scatter ---------------------------
__global__ void hist_kernel(const int* __restrict__ eidx, int* __restrict__ cnt, int E)
{
  int e = blockIdx.x*blockDim.x + threadIdx.x;
  for (; e < E; e += gridDim.x*blockDim.x)
    atomicAdd(&cnt[eidx[e]], 1);
}

// single-block exclusive scan (256 threads, wave shfl scan + cross-wave LDS)
__global__ void scan_kernel(const int* __restrict__ cnt, int* __restrict__ rowptr,
                            int* __restrict__ cursor, int N, int E)
{
  __shared__ int wsum[4];
  __shared__ int carry;
  const int lane = threadIdx.x & 63, w = threadIdx.x >> 6;
  if (threadIdx.x == 0) carry = 0;
  __syncthreads();
  for (int base = 0; base < N; base += 256){
    int i = base + (int)threadIdx.x;
    int v = (i < N) ? cnt[i] : 0;
    int s = v;
#pragma unroll
    for (int off = 1; off < 64; off <<= 1){
      int t = __shfl_up(s, off);
      if (lane >= off) s += t;
    }
    if (lane == 63) wsum[w] = s;
    __syncthreads();
    int pre = carry;
    for (int j = 0; j < w; ++j) pre += wsum[j];
    int excl = pre + s - v;
    if (i < N){ rowptr[i] = excl; cursor[i] = excl; }
    __syncthreads();
    if (threadIdx.x == 255) carry = pre + s;
    __syncthreads();
  }
  if (threadIdx.x == 0) rowptr[N] = E;
}

__global__ void scatter_kernel(const int* __restrict__ eidx, const float* __restrict__ ep,
                               int* __restrict__ cursor, u32x2* __restrict__ recs, int E)
{
  int e = blockIdx.x*blockDim.x + threadIdx.x;
  for (; e < E; e += gridDim.x*blockDim.x){
    int r = eidx[e];
    int c = eidx[E + e];
    float p0 = ep[e], p1 = ep[E + e];
    int slot = atomicAdd(&cursor[r], 1);
    u32x2 rec; rec[0] = (u32)c; rec[1] = pkrtz(p0, p1);
    recs[slot] = rec;
  }
}

// one edge-type's 2-layer MLP on 32 edges (swapped-operand MFMA), accumulate into msg.
#define EDGE_TYPE(T, PT) do{                                                 \
    f32x16 accA_[2];                                                         \
    _Pragma("unroll")                                                        \
    for (int mt=0; mt<2; ++mt){                                              \
      f16x8 Ab_ = __builtin_bit_cast(f16x8,(u32x4){ b1w[T][mt],0u,0u,0u });  \
      f32x16 a_ = MFMA(Ab_, Bb, zacc);                                       \
      _Pragma("unroll")                                                      \
      for (int kc=0;kc<4;kc++) a_ = MFMA(w1f[T][mt][kc], bfrag[kc], a_);     \
      accA_[mt] = a_;                                                        \
    }                                                                        \
    u32 pk_[2][8];                                                           \
    _Pragma("unroll")                                                        \
    for (int mt=0; mt<2; ++mt)                                               \
      _Pragma("unroll")                                                      \
      for (int p=0;p<8;p++)                                                  \
        pk_[mt][p] = pkrtz(fmaxf(accA_[mt][2*p],0.f),                        \
                           fmaxf(accA_[mt][2*p+1],0.f));                     \
    f16x8 b2f_[4];                                                           \
    _Pragma("unroll")                                                        \
    for (int kc=0;kc<4;kc++){                                                \
      int ms_=kc>>1, A_=(kc&1)*4;                                            \
      u32x2 s0_=plswap(pk_[ms_][A_+0],pk_[ms_][A_+2]);                       \
      u32x2 s1_=plswap(pk_[ms_][A_+1],pk_[ms_][A_+3]);                       \
      b2f_[kc]=__builtin_bit_cast(f16x8,(u32x4){s0_[0],s1_[0],s0_[1],s1_[1]});\
    }                                                                        \
    _Pragma("unroll")                                                        \
    for (int mt=0; mt<2; ++mt){                                              \
      f16x8 Ab2_=__builtin_bit_cast(f16x8,(u32x4){ b2w[T][mt],0u,0u,0u });   \
      f32x16 c_=MFMA(Ab2_, Bb, zacc);                                        \
      _Pragma("unroll")                                                      \
      for (int kc=0;kc<4;kc++) c_=MFMA(w2f[T][mt][kc], b2f_[kc], c_);        \
      _Pragma("unroll")                                                      \
      for (int i=0;i<16;i++) msg[mt][i] += (PT)*fmaxf(c_[i],0.f);            \
    }                                                                        \
  } while(0)

// ---------------- edge kernel: one wave per node, CSR, NO atomics -------------------
__global__ __launch_bounds__(256,2) void edge_csr_kernel(
    const float* __restrict__ x, const int* __restrict__ rowptr,
    const u32x2* __restrict__ recs, const u32* __restrict__ pw,
    float* __restrict__ agg, int N)
{
  const int wid = threadIdx.x>>6, lane = threadIdx.x&63;
  const int h = lane>>5, e32 = lane&31;
  const int gwave = blockIdx.x*4 + wid;
  const int nwaves = gridDim.x*4;

  __shared__ float buf[4][64];

  const u32x4* pw4 = (const u32x4*)pw;
  f16x8 w1f[2][2][4], w2f[2][2][4];
#pragma unroll
  for (int t=0;t<2;t++)
#pragma unroll
   for (int mt=0;mt<2;mt++)
#pragma unroll
    for (int kc=0;kc<4;kc++){
      w1f[t][mt][kc] = __builtin_bit_cast(f16x8, pw4[(W1T_OFF>>2) + ((t*2+mt)*4+kc)*64 + lane]);
      w2f[t][mt][kc] = __builtin_bit_cast(f16x8, pw4[(W2T_OFF>>2) + ((t*2+mt)*4+kc)*64 + lane]);
    }
  u32 b1w[2][2], b2w[2][2];
#pragma unroll
  for (int t=0;t<2;t++)
#pragma unroll
   for (int mt=0;mt<2;mt++){
     b1w[t][mt] = pw[B1F_OFF + t*128 + mt*64 + lane];
     b2w[t][mt] = pw[B2F_OFF + t*128 + mt*64 + lane];
   }
  const f16x8 Bb = __builtin_bit_cast(f16x8, (u32x4){ (h==0)?0x3C00u:0u, 0u, 0u, 0u });
  f32x16 zacc;
#pragma unroll
  for (int i=0;i<16;i++) zacc[i]=0.f;

  for (int n = gwave; n < N; n += nwaves){
    const int s    = rowptr[n];
    const int eend = rowptr[n+1];

    // pre_msg^T B-frags, kc=0,1: x[n] (same for all edges of this node)
    f16x8 bfrag[4];
#pragma unroll
    for (int kc=0;kc<2;kc++){
      const f32x4* xp = (const f32x4*)(x + ((size_t)n<<5) + (kc<<4) + (h<<3));
      f32x4 a = xp[0], b = xp[1];
      bfrag[kc] = __builtin_bit_cast(f16x8, (u32x4){ pkrtz(a[0],a[1]), pkrtz(a[2],a[3]),
                                                     pkrtz(b[0],b[1]), pkrtz(b[2],b[3]) });
    }

    float msg[2][16];
#pragma unroll
    for (int mt=0;mt<2;mt++)
#pragma unroll
     for (int i=0;i<16;i++) msg[mt][i]=0.f;

    for (int off = s; off < eend; off += 32){
      int idx = off + e32;
      bool valid = idx < eend;
      u32x2 rec = recs[valid ? idx : s];
      int cnode = (int)rec[0];
      half2_t ph = h2u(rec[1]);
      float p0 = valid ? (float)ph[0] : 0.f;
      float p1 = valid ? (float)ph[1] : 0.f;

      // kc=2,3: x[c] gather
#pragma unroll
      for (int kc=2;kc<4;kc++){
        const f32x4* xp = (const f32x4*)(x + ((size_t)cnode<<5) + ((kc&1)<<4) + (h<<3));
        f32x4 a = xp[0], b = xp[1];
        bfrag[kc] = __builtin_bit_cast(f16x8, (u32x4){ pkrtz(a[0],a[1]), pkrtz(a[2],a[3]),
                                                       pkrtz(b[0],b[1]), pkrtz(b[2],b[3]) });
      }

      EDGE_TYPE(0, p0);
      EDGE_TYPE(1, p1);
    }

    // butterfly sum over the 32 edge lanes (within each 32-lane half)
#pragma unroll
    for (int mt=0;mt<2;mt++)
#pragma unroll
     for (int i=0;i<16;i++){
       float v = msg[mt][i];
       v += __shfl_xor(v, 1);
       v += __shfl_xor(v, 2);
       v += __shfl_xor(v, 4);
       v += __shfl_xor(v, 8);
       v += __shfl_xor(v, 16);
       msg[mt][i] = v;
     }

    // lanes 0 and 32 write their half's 32 feats to LDS, then all lanes store agg
    if (e32 == 0){
#pragma unroll
      for (int mt=0;mt<2;mt++)
#pragma unroll
       for (int p=0;p<8;p++){
         int feat = mt*32 + ((2*p)&3) + 8*(p>>1) + 4*h;
         float2 v2; v2.x = msg[mt][2*p]; v2.y = msg[mt][2*p+1];
         *(float2*)(&buf[wid][feat]) = v2;
       }
    }
    asm volatile("s_waitcnt lgkmcnt(0)" ::: "memory");
    agg[((size_t)n<<6) + lane] = buf[wid][lane];
  }
}

// ---------------- node kernel: persistent waves, lane = output feature --------------
__global__ __launch_bounds__(256,2) void node_kernel(
    const float* __restrict__ x, const float* __restrict__ agg,
    const u32* __restrict__ pw, float* __restrict__ out, int N)
{
  const int wid=threadIdx.x>>6, lane=threadIdx.x&63;
  const int gwave = blockIdx.x*4 + wid;
  const int nwaves = gridDim.x*4;
  __shared__ __align__(16) u16 aug_lds[4][96];
  __shared__ __align__(16) u16 h_lds[4][64];

  u32 wo1r[48], wo2r[32], wo3r[32];
#pragma unroll
  for (int kk=0;kk<48;++kk) wo1r[kk]=pw[NWO1_OFF + kk*64 + lane];
#pragma unroll
  for (int kk=0;kk<32;++kk) wo2r[kk]=pw[NWO2_OFF + kk*64 + lane];
#pragma unroll
  for (int kk=0;kk<32;++kk) wo3r[kk]=pw[NWO3_OFF + kk*32 + (lane&31)];
  const float* nb=(const float*)(pw+NB_OFF);
  float bo1r=nb[lane], bo2r=nb[64+lane], bo3r=nb[128+(lane&31)];

  for (int node = gwave; node < N; node += nwaves){
    float xv=0.f;
    if (lane<32){ xv=x[(size_t)node*32+lane]; aug_lds[wid][lane]=f2h_bits(xv); }
    aug_lds[wid][32+lane]=f2h_bits(agg[(size_t)node*64+lane]);

    const half2_t* aug2=(const half2_t*)aug_lds[wid];
    float s0=bo1r,s1=0.f,s2=0.f,s3=0.f;
#pragma unroll
    for (int kk=0;kk<48;kk+=4){
      s0=FDOT2(aug2[kk+0],h2u(wo1r[kk+0]),s0);
      s1=FDOT2(aug2[kk+1],h2u(wo1r[kk+1]),s1);
      s2=FDOT2(aug2[kk+2],h2u(wo1r[kk+2]),s2);
      s3=FDOT2(aug2[kk+3],h2u(wo1r[kk+3]),s3);
    }
    h_lds[wid][lane]=f2h_bits(fmaxf((s0+s1)+(s2+s3),0.f));
    const half2_t* hp=(const half2_t*)h_lds[wid];
    float t0=bo2r,t1=0.f,t2=0.f,t3=0.f;
#pragma unroll
    for (int kk=0;kk<32;kk+=4){
      t0=FDOT2(hp[kk+0],h2u(wo2r[kk+0]),t0);
      t1=FDOT2(hp[kk+1],h2u(wo2r[kk+1]),t1);
      t2=FDOT2(hp[kk+2],h2u(wo2r[kk+2]),t2);
      t3=FDOT2(hp[kk+3],h2u(wo2r[kk+3]),t3);
    }
    float h2v=fmaxf((t0+t1)+(t2+t3),0.f);
    h_lds[wid][lane]=f2h_bits(h2v);   // same-wave in-order LDS: reads above already done
    if (lane<32){
      float r0=bo3r,r1=0.f,r2=0.f,r3=0.f;
#pragma unroll
      for (int kk=0;kk<32;kk+=4){
        r0=FDOT2(hp[kk+0],h2u(wo3r[kk+0]),r0);
        r1=FDOT2(hp[kk+1],h2u(wo3r[kk+1]),r1);
        r2=FDOT2(hp[kk+2],h2u(wo3r[kk+2]),r2);
        r3=FDOT2(hp[kk+3],h2u(wo3r[kk+3]),r3);
      }
      out[(size_t)node*32+lane]=((r0+r1)+(r2+r3))+xv;
    }
  }
}

extern "C" void kernel_launch(void* const* d_in, const int* in_sizes, int n_in,
                              void* d_out, int out_size, void* d_ws, size_t ws_size,
                              hipStream_t stream)
{
  const float* x   = (const float*)d_in[0];
  const float* ep  = (const float*)d_in[1];
  const float* W1  = (const float*)d_in[2];
  const float* b1  = (const float*)d_in[3];
  const float* W2  = (const float*)d_in[4];
  const float* b2  = (const float*)d_in[5];
  const float* Wo1 = (const float*)d_in[6];
  const float* bo1 = (const float*)d_in[7];
  const float* Wo2 = (const float*)d_in[8];
  const float* bo2 = (const float*)d_in[9];
  const float* Wo3 = (const float*)d_in[10];
  const float* bo3 = (const float*)d_in[11];
  const int* eidx  = (const int*)d_in[12];

  int N = in_sizes[0]/32;
  int E = in_sizes[12]/2;

  // workspace layout (256B-aligned regions)
  auto rnd = [](size_t v){ return (v + 255) & ~(size_t)255; };
  size_t cnt_off    = 0;
  size_t rowptr_off = rnd(cnt_off    + (size_t)N*4);
  size_t cursor_off = rnd(rowptr_off + (size_t)(N+1)*4);
  size_t agg_off    = rnd(cursor_off + (size_t)N*4);
  size_t pw_off     = rnd(agg_off    + (size_t)N*64*4);
  size_t rec_off    = rnd(pw_off     + (size_t)PW_WORDS*4);

  char* ws = (char*)d_ws;
  int*   cnt    = (int*)(ws + cnt_off);
  int*   rowptr = (int*)(ws + rowptr_off);
  int*   cursor = (int*)(ws + cursor_off);
  float* agg    = (float*)(ws + agg_off);
  u32*   pw     = (u32*)(ws + pw_off);
  u32x2* recs   = (u32x2*)(ws + rec_off);

  hipMemsetAsync(cnt, 0, (size_t)N*4, stream);
  prep_kernel<<<64, 256, 0, stream>>>(W1,b1,W2,b2,Wo1,bo1,Wo2,bo2,Wo3,bo3,pw);
  hist_kernel<<<1024, 256, 0, stream>>>(eidx, cnt, E);
  scan_kernel<<<1, 256, 0, stream>>>(cnt, rowptr, cursor, N, E);
  scatter_kernel<<<1024, 256, 0, stream>>>(eidx, ep, cursor, recs, E);
  edge_csr_kernel<<<512, 256, 0, stream>>>(x, rowptr, recs, pw, agg, N);
  node_kernel<<<512, 256, 0, stream>>>(x, agg, pw, (float*)d_out, N);
}

// Round 6
// 422.946 us; speedup vs baseline: 1.4301x; 1.4301x over previous
//
#include <hip/hip_runtime.h>

typedef unsigned short u16;
typedef unsigned int   u32;
typedef _Float16 half2_t __attribute__((ext_vector_type(2)));
typedef _Float16 f16x8  __attribute__((ext_vector_type(8)));
typedef float    f32x16 __attribute__((ext_vector_type(16)));
typedef float    f32x4  __attribute__((ext_vector_type(4)));
typedef unsigned u32x4  __attribute__((ext_vector_type(4)));
typedef unsigned u32x2  __attribute__((ext_vector_type(2)));

// packed-weight layout (u32 word indices within pw region)
#define W1T_OFF   0        // [t][mt][kc][lane][4] MFMA A-frags of W1^T (f16 pairs)
#define W2T_OFF   4096
#define B1F_OFF   8192     // [t][mt][lane] bias A-frag word
#define B2F_OFF   8448
#define NWO1_OFF  8704     // node MLP: [48][64] f16-pairs over k
#define NWO2_OFF  11776    // [32][64]
#define NWO3_OFF  13824    // [32][32]
#define NB_OFF    14848    // floats: bo1[64] bo2[64] bo3[32]
#define PW_WORDS  15008

__device__ __forceinline__ u16 f2h_bits(float f){ _Float16 h=(_Float16)f; return __builtin_bit_cast(u16,h); }
__device__ __forceinline__ half2_t h2u(u32 u){ return __builtin_bit_cast(half2_t,u); }

__device__ __forceinline__ u32 pkrtz(float a, float b){
#if defined(__has_builtin)
#if __has_builtin(__builtin_amdgcn_cvt_pkrtz)
  auto r = __builtin_amdgcn_cvt_pkrtz(a,b);
  return __builtin_bit_cast(u32, r);
#else
  return (u32)f2h_bits(a) | ((u32)f2h_bits(b)<<16);
#endif
#else
  return (u32)f2h_bits(a) | ((u32)f2h_bits(b)<<16);
#endif
}

// permlane32_swap: out0 = {a.lo32, b.lo32}, out1 = {a.hi32, b.hi32}
__device__ __forceinline__ u32x2 plswap(u32 a, u32 b){
#if defined(__has_builtin)
#if __has_builtin(__builtin_amdgcn_permlane32_swap)
  return __builtin_amdgcn_permlane32_swap(a, b, false, false);
#else
  u32 pa = (u32)__shfl_xor((int)a, 32);
  u32 pb = (u32)__shfl_xor((int)b, 32);
  int hh = (int)((threadIdx.x & 63) >> 5);
  u32x2 r; r[0] = hh ? pb : a; r[1] = hh ? b : pa; return r;
#endif
#else
  u32 pa = (u32)__shfl_xor((int)a, 32);
  u32 pb = (u32)__shfl_xor((int)b, 32);
  int hh = (int)((threadIdx.x & 63) >> 5);
  u32x2 r; r[0] = hh ? pb : a; r[1] = hh ? b : pa; return r;
#endif
}

#define MFMA(A,B,C) __builtin_amdgcn_mfma_f32_32x32x16_f16((A),(B),(C),0,0,0)

#if defined(__has_builtin)
#if __has_builtin(__builtin_amdgcn_fdot2)
#define FDOT2(a,b,c) __builtin_amdgcn_fdot2((a),(b),(c),false)
#endif
#endif
#ifndef FDOT2
#define FDOT2(a,b,c) (fmaf((float)(a)[1],(float)(b)[1], fmaf((float)(a)[0],(float)(b)[0],(c))))
#endif

// ---------------- prep: pack weights into MFMA frag / dot2 layouts ------------------
__global__ void prep_kernel(const float* __restrict__ W1, const float* __restrict__ b1,
                            const float* __restrict__ W2, const float* __restrict__ b2,
                            const float* __restrict__ Wo1, const float* __restrict__ bo1,
                            const float* __restrict__ Wo2, const float* __restrict__ bo2,
                            const float* __restrict__ Wo3, const float* __restrict__ bo3,
                            u32* __restrict__ pw)
{
  int i = blockIdx.x*blockDim.x + threadIdx.x;
  for (; i < PW_WORDS; i += gridDim.x*blockDim.x) {
    if (i < 4096) {                         // W1^T A-frags
      int r=i&3, lane=(i>>2)&63, kc=(i>>8)&3, mt=(i>>10)&1, t=(i>>11)&1;
      int h=lane>>5, feat=mt*32+(lane&31);
      int k0=kc*16 + h*8 + 2*r;
      float lo=W1[t*4096 + k0*64 + feat], hi=W1[t*4096 + (k0+1)*64 + feat];
      pw[W1T_OFF+i] = (u32)f2h_bits(lo) | ((u32)f2h_bits(hi)<<16);
    } else if (i < 8192) {                  // W2^T A-frags
      int q=i-4096;
      int r=q&3, lane=(q>>2)&63, kc=(q>>8)&3, mt=(q>>10)&1, t=(q>>11)&1;
      int h=lane>>5, feat=mt*32+(lane&31);
      int k0=kc*16 + h*8 + 2*r;
      float lo=W2[t*4096 + k0*64 + feat], hi=W2[t*4096 + (k0+1)*64 + feat];
      pw[i] = (u32)f2h_bits(lo) | ((u32)f2h_bits(hi)<<16);
    } else if (i < 8448) {                  // b1 bias frag word
      int q=i-8192; int lane=q&63, mt=(q>>6)&1, t=(q>>7)&1;
      pw[i] = (lane<32) ? (u32)f2h_bits(b1[t*64 + mt*32 + (lane&31)]) : 0u;
    } else if (i < 8704) {                  // b2 bias frag word
      int q=i-8448; int lane=q&63, mt=(q>>6)&1, t=(q>>7)&1;
      pw[i] = (lane<32) ? (u32)f2h_bits(b2[t*64 + mt*32 + (lane&31)]) : 0u;
    } else if (i < 11776) {                 // node Wo1 [48 kk][64 j]
      int q=i-NWO1_OFF, kk=q>>6, j=q&63;
      pw[i] = (u32)f2h_bits(Wo1[(2*kk)*64 + j]) | ((u32)f2h_bits(Wo1[(2*kk+1)*64 + j])<<16);
    } else if (i < 13824) {                 // node Wo2 [32][64]
      int q=i-NWO2_OFF, kk=q>>6, j=q&63;
      pw[i] = (u32)f2h_bits(Wo2[(2*kk)*64 + j]) | ((u32)f2h_bits(Wo2[(2*kk+1)*64 + j])<<16);
    } else if (i < 14848) {                 // node Wo3 [32][32]
      int q=i-NWO3_OFF, kk=q>>5, j=q&31;
      pw[i] = (u32)f2h_bits(Wo3[(2*kk)*32 + j]) | ((u32)f2h_bits(Wo3[(2*kk+1)*32 + j])<<16);
    } else {                                // node biases f32
      int q = i - NB_OFF;
      float* nb = (float*)(pw + NB_OFF);
      float v;
      if (q < 64)       v = bo1[q];
      else if (q < 128) v = bo2[q-64];
      else              v = bo3[q-128];
      nb[q] = v;
    }
  }
}

// ---------------- CSR build: histogram -> 3-phase scan -> scatter -------------------
__global__ void hist_kernel(const int* __restrict__ eidx, int* __restrict__ cnt, int E)
{
  int e = blockIdx.x*blockDim.x + threadIdx.x;
  for (; e < E; e += gridDim.x*blockDim.x)
    atomicAdd(&cnt[eidx[e]], 1);
}

// per-256-chunk exclusive scan; writes local excl to rowptr, chunk totals to ctot
__global__ void scan1_kernel(const int* __restrict__ cnt, int* __restrict__ rowptr,
                             int* __restrict__ ctot, int N)
{
  __shared__ int wsum[4];
  const int tid = threadIdx.x, lane = tid & 63, w = tid >> 6;
  int i = blockIdx.x*256 + tid;
  int v = (i < N) ? cnt[i] : 0;
  int s = v;
#pragma unroll
  for (int off = 1; off < 64; off <<= 1){
    int t = __shfl_up(s, off);
    if (lane >= off) s += t;
  }
  if (lane == 63) wsum[w] = s;
  __syncthreads();
  int pre = 0;
  for (int j = 0; j < w; ++j) pre += wsum[j];
  if (i < N) rowptr[i] = pre + s - v;
  if (tid == 255) ctot[blockIdx.x] = pre + s;
}

// single block scans chunk totals (nc <= 256) into coff; sets rowptr[N]=E
__global__ void scan2_kernel(const int* __restrict__ ctot, int* __restrict__ coff,
                             int* __restrict__ rowptr, int nc, int N, int E)
{
  __shared__ int wsum[4];
  const int tid = threadIdx.x, lane = tid & 63, w = tid >> 6;
  int v = (tid < nc) ? ctot[tid] : 0;
  int s = v;
#pragma unroll
  for (int off = 1; off < 64; off <<= 1){
    int t = __shfl_up(s, off);
    if (lane >= off) s += t;
  }
  if (lane == 63) wsum[w] = s;
  __syncthreads();
  int pre = 0;
  for (int j = 0; j < w; ++j) pre += wsum[j];
  if (tid < nc) coff[tid] = pre + s - v;
  if (tid == 0) rowptr[N] = E;
}

__global__ void scan3_kernel(int* __restrict__ rowptr, const int* __restrict__ coff,
                             int* __restrict__ cursor, int N)
{
  int i = blockIdx.x*256 + threadIdx.x;
  if (i < N){
    int r = rowptr[i] + coff[i >> 8];
    rowptr[i] = r;
    cursor[i] = r;
  }
}

__global__ void scatter_kernel(const int* __restrict__ eidx, const float* __restrict__ ep,
                               int* __restrict__ cursor, u32x2* __restrict__ recs, int E)
{
  int e = blockIdx.x*blockDim.x + threadIdx.x;
  for (; e < E; e += gridDim.x*blockDim.x){
    int r = eidx[e];
    int c = eidx[E + e];
    float p0 = ep[e], p1 = ep[E + e];
    int slot = atomicAdd(&cursor[r], 1);
    u32x2 rec; rec[0] = (u32)c; rec[1] = pkrtz(p0, p1);
    recs[slot] = rec;
  }
}

// one edge-type's 2-layer MLP on 32 edges (swapped-operand MFMA), accumulate into msg.
#define EDGE_TYPE(T, PT) do{                                                 \
    f32x16 accA_[2];                                                         \
    _Pragma("unroll")                                                        \
    for (int mt=0; mt<2; ++mt){                                              \
      f16x8 Ab_ = __builtin_bit_cast(f16x8,(u32x4){ b1w[T][mt],0u,0u,0u });  \
      f32x16 a_ = MFMA(Ab_, Bb, zacc);                                       \
      _Pragma("unroll")                                                      \
      for (int kc=0;kc<4;kc++) a_ = MFMA(w1f[T][mt][kc], bfrag[kc], a_);     \
      accA_[mt] = a_;                                                        \
    }                                                                        \
    u32 pk_[2][8];                                                           \
    _Pragma("unroll")                                                        \
    for (int mt=0; mt<2; ++mt)                                               \
      _Pragma("unroll")                                                      \
      for (int p=0;p<8;p++)                                                  \
        pk_[mt][p] = pkrtz(fmaxf(accA_[mt][2*p],0.f),                        \
                           fmaxf(accA_[mt][2*p+1],0.f));                     \
    f16x8 b2f_[4];                                                           \
    _Pragma("unroll")                                                        \
    for (int kc=0;kc<4;kc++){                                                \
      int ms_=kc>>1, A_=(kc&1)*4;                                            \
      u32x2 s0_=plswap(pk_[ms_][A_+0],pk_[ms_][A_+2]);                       \
      u32x2 s1_=plswap(pk_[ms_][A_+1],pk_[ms_][A_+3]);                       \
      b2f_[kc]=__builtin_bit_cast(f16x8,(u32x4){s0_[0],s1_[0],s0_[1],s1_[1]});\
    }                                                                        \
    _Pragma("unroll")                                                        \
    for (int mt=0; mt<2; ++mt){                                              \
      f16x8 Ab2_=__builtin_bit_cast(f16x8,(u32x4){ b2w[T][mt],0u,0u,0u });   \
      f32x16 c_=MFMA(Ab2_, Bb, zacc);                                        \
      _Pragma("unroll")                                                      \
      for (int kc=0;kc<4;kc++) c_=MFMA(w2f[T][mt][kc], b2f_[kc], c_);        \
      _Pragma("unroll")                                                      \
      for (int i=0;i<16;i++) msg[mt][i] += (PT)*fmaxf(c_[i],0.f);            \
    }                                                                        \
  } while(0)

// ---------------- edge kernel: wave/node CSR, pipelined, LDS transpose-reduce -------
__global__ __launch_bounds__(256,2) void edge_csr_kernel(
    const float* __restrict__ x, const int* __restrict__ rowptr,
    const u32x2* __restrict__ recs, const u32* __restrict__ pw,
    float* __restrict__ agg, int N)
{
  const int wid = threadIdx.x>>6, lane = threadIdx.x&63;
  const int h = lane>>5, e32 = lane&31;
  const int gwave = blockIdx.x*4 + wid;
  const int nwaves = gridDim.x*4;

  __shared__ float msg_lds[4][32*66];
  float* ml = msg_lds[wid];

  const u32x4* pw4 = (const u32x4*)pw;
  f16x8 w1f[2][2][4], w2f[2][2][4];
#pragma unroll
  for (int t=0;t<2;t++)
#pragma unroll
   for (int mt=0;mt<2;mt++)
#pragma unroll
    for (int kc=0;kc<4;kc++){
      w1f[t][mt][kc] = __builtin_bit_cast(f16x8, pw4[(W1T_OFF>>2) + ((t*2+mt)*4+kc)*64 + lane]);
      w2f[t][mt][kc] = __builtin_bit_cast(f16x8, pw4[(W2T_OFF>>2) + ((t*2+mt)*4+kc)*64 + lane]);
    }
  u32 b1w[2][2], b2w[2][2];
#pragma unroll
  for (int t=0;t<2;t++)
#pragma unroll
   for (int mt=0;mt<2;mt++){
     b1w[t][mt] = pw[B1F_OFF + t*128 + mt*64 + lane];
     b2w[t][mt] = pw[B2F_OFF + t*128 + mt*64 + lane];
   }
  const f16x8 Bb = __builtin_bit_cast(f16x8, (u32x4){ (h==0)?0x3C00u:0u, 0u, 0u, 0u });
  f32x16 zacc;
#pragma unroll
  for (int i=0;i<16;i++) zacc[i]=0.f;

  for (int n = gwave; n < N; n += nwaves){
    const int s    = rowptr[n];
    const int eend = rowptr[n+1];

    // x[n] -> bfrag kc=0,1 (constant over this node's groups)
    f16x8 bfrag[4];
#pragma unroll
    for (int kc=0;kc<2;kc++){
      const f32x4* xp = (const f32x4*)(x + ((size_t)n<<5) + (kc<<4) + (h<<3));
      f32x4 a = xp[0], b = xp[1];
      bfrag[kc] = __builtin_bit_cast(f16x8, (u32x4){ pkrtz(a[0],a[1]), pkrtz(a[2],a[3]),
                                                     pkrtz(b[0],b[1]), pkrtz(b[2],b[3]) });
    }

    float msg[2][16];
#pragma unroll
    for (int mt=0;mt<2;mt++)
#pragma unroll
     for (int i=0;i<16;i++) msg[mt][i]=0.f;

    // prologue: first group's rec + raw x[c] gather
    u32x2 rc; rc[0]=0u; rc[1]=0u;
    f32x4 ga[4];
    if (s < eend){
      int idx = s + e32;
      rc = recs[(idx < eend) ? idx : s];
      int cn = (int)rc[0];
      const f32x4* xp0 = (const f32x4*)(x + ((size_t)cn<<5) + (h<<3));
      const f32x4* xp1 = (const f32x4*)(x + ((size_t)cn<<5) + 16 + (h<<3));
      ga[0]=xp0[0]; ga[1]=xp0[1]; ga[2]=xp1[0]; ga[3]=xp1[1];
    }

    for (int off = s; off < eend; off += 32){
      const bool cur_valid = (off + e32) < eend;
      const bool have_next = (off + 32) < eend;
      u32x2 rn; rn[0]=0u; rn[1]=0u;
      if (have_next){                         // prefetch next group's rec
        int idx = off + 32 + e32;
        rn = recs[(idx < eend) ? idx : s];
      }
      half2_t ph = h2u(rc[1]);
      float p0 = cur_valid ? (float)ph[0] : 0.f;
      float p1 = cur_valid ? (float)ph[1] : 0.f;

      // convert current raw gather -> bfrag kc=2,3
      bfrag[2] = __builtin_bit_cast(f16x8, (u32x4){ pkrtz(ga[0][0],ga[0][1]), pkrtz(ga[0][2],ga[0][3]),
                                                    pkrtz(ga[1][0],ga[1][1]), pkrtz(ga[1][2],ga[1][3]) });
      bfrag[3] = __builtin_bit_cast(f16x8, (u32x4){ pkrtz(ga[2][0],ga[2][1]), pkrtz(ga[2][2],ga[2][3]),
                                                    pkrtz(ga[3][0],ga[3][1]), pkrtz(ga[3][2],ga[3][3]) });

      EDGE_TYPE(0, p0);

      if (have_next){                         // issue next group's gather under type-1 work
        int cn = (int)rn[0];
        const f32x4* xp0 = (const f32x4*)(x + ((size_t)cn<<5) + (h<<3));
        const f32x4* xp1 = (const f32x4*)(x + ((size_t)cn<<5) + 16 + (h<<3));
        ga[0]=xp0[0]; ga[1]=xp0[1]; ga[2]=xp1[0]; ga[3]=xp1[1];
      }

      EDGE_TYPE(1, p1);

      rc = rn;
    }

    // transpose via padded LDS (wave-local), column-sum, single store
#pragma unroll
    for (int mt=0;mt<2;mt++)
#pragma unroll
     for (int p=0;p<8;p++){
       int feat = mt*32 + ((2*p)&3) + 8*(p>>1) + 4*h;
       float2 v2; v2.x = msg[mt][2*p]; v2.y = msg[mt][2*p+1];
       *(float2*)(ml + e32*66 + feat) = v2;
     }
    asm volatile("s_waitcnt lgkmcnt(0)" ::: "memory");
    float acc = 0.f;
#pragma unroll
    for (int e=0;e<32;e++) acc += ml[e*66 + lane];
    agg[((size_t)n<<6) + lane] = acc;
  }
}

// ---------------- node kernel: persistent waves, lane = output feature --------------
__global__ __launch_bounds__(256,2) void node_kernel(
    const float* __restrict__ x, const float* __restrict__ agg,
    const u32* __restrict__ pw, float* __restrict__ out, int N)
{
  const int wid=threadIdx.x>>6, lane=threadIdx.x&63;
  const int gwave = blockIdx.x*4 + wid;
  const int nwaves = gridDim.x*4;
  __shared__ __align__(16) u16 aug_lds[4][96];
  __shared__ __align__(16) u16 h_lds[4][64];

  u32 wo1r[48], wo2r[32], wo3r[32];
#pragma unroll
  for (int kk=0;kk<48;++kk) wo1r[kk]=pw[NWO1_OFF + kk*64 + lane];
#pragma unroll
  for (int kk=0;kk<32;++kk) wo2r[kk]=pw[NWO2_OFF + kk*64 + lane];
#pragma unroll
  for (int kk=0;kk<32;++kk) wo3r[kk]=pw[NWO3_OFF + kk*32 + (lane&31)];
  const float* nb=(const float*)(pw+NB_OFF);
  float bo1r=nb[lane], bo2r=nb[64+lane], bo3r=nb[128+(lane&31)];

  for (int node = gwave; node < N; node += nwaves){
    float xv=0.f;
    if (lane<32){ xv=x[(size_t)node*32+lane]; aug_lds[wid][lane]=f2h_bits(xv); }
    aug_lds[wid][32+lane]=f2h_bits(agg[(size_t)node*64+lane]);

    const half2_t* aug2=(const half2_t*)aug_lds[wid];
    float s0=bo1r,s1=0.f,s2=0.f,s3=0.f;
#pragma unroll
    for (int kk=0;kk<48;kk+=4){
      s0=FDOT2(aug2[kk+0],h2u(wo1r[kk+0]),s0);
      s1=FDOT2(aug2[kk+1],h2u(wo1r[kk+1]),s1);
      s2=FDOT2(aug2[kk+2],h2u(wo1r[kk+2]),s2);
      s3=FDOT2(aug2[kk+3],h2u(wo1r[kk+3]),s3);
    }
    h_lds[wid][lane]=f2h_bits(fmaxf((s0+s1)+(s2+s3),0.f));
    const half2_t* hp=(const half2_t*)h_lds[wid];
    float t0=bo2r,t1=0.f,t2=0.f,t3=0.f;
#pragma unroll
    for (int kk=0;kk<32;kk+=4){
      t0=FDOT2(hp[kk+0],h2u(wo2r[kk+0]),t0);
      t1=FDOT2(hp[kk+1],h2u(wo2r[kk+1]),t1);
      t2=FDOT2(hp[kk+2],h2u(wo2r[kk+2]),t2);
      t3=FDOT2(hp[kk+3],h2u(wo2r[kk+3]),t3);
    }
    float h2v=fmaxf((t0+t1)+(t2+t3),0.f);
    h_lds[wid][lane]=f2h_bits(h2v);   // same-wave in-order LDS: reads above already done
    if (lane<32){
      float r0=bo3r,r1=0.f,r2=0.f,r3=0.f;
#pragma unroll
      for (int kk=0;kk<32;kk+=4){
        r0=FDOT2(hp[kk+0],h2u(wo3r[kk+0]),r0);
        r1=FDOT2(hp[kk+1],h2u(wo3r[kk+1]),r1);
        r2=FDOT2(hp[kk+2],h2u(wo3r[kk+2]),r2);
        r3=FDOT2(hp[kk+3],h2u(wo3r[kk+3]),r3);
      }
      out[(size_t)node*32+lane]=((r0+r1)+(r2+r3))+xv;
    }
  }
}

extern "C" void kernel_launch(void* const* d_in, const int* in_sizes, int n_in,
                              void* d_out, int out_size, void* d_ws, size_t ws_size,
                              hipStream_t stream)
{
  const float* x   = (const float*)d_in[0];
  const float* ep  = (const float*)d_in[1];
  const float* W1  = (const float*)d_in[2];
  const float* b1  = (const float*)d_in[3];
  const float* W2  = (const float*)d_in[4];
  const float* b2  = (const float*)d_in[5];
  const float* Wo1 = (const float*)d_in[6];
  const float* bo1 = (const float*)d_in[7];
  const float* Wo2 = (const float*)d_in[8];
  const float* bo2 = (const float*)d_in[9];
  const float* Wo3 = (const float*)d_in[10];
  const float* bo3 = (const float*)d_in[11];
  const int* eidx  = (const int*)d_in[12];

  int N = in_sizes[0]/32;
  int E = in_sizes[12]/2;
  int nchunks = (N + 255) / 256;          // 196 for N=50000 (<=256 required by scan2)

  // workspace layout (256B-aligned regions)
  auto rnd = [](size_t v){ return (v + 255) & ~(size_t)255; };
  size_t cnt_off    = 0;
  size_t rowptr_off = rnd(cnt_off    + (size_t)N*4);
  size_t cursor_off = rnd(rowptr_off + (size_t)(N+1)*4);
  size_t ctot_off   = rnd(cursor_off + (size_t)N*4);
  size_t coff_off   = rnd(ctot_off   + (size_t)nchunks*4);
  size_t agg_off    = rnd(coff_off   + (size_t)nchunks*4);
  size_t pw_off     = rnd(agg_off    + (size_t)N*64*4);
  size_t rec_off    = rnd(pw_off     + (size_t)PW_WORDS*4);

  char* ws = (char*)d_ws;
  int*   cnt    = (int*)(ws + cnt_off);
  int*   rowptr = (int*)(ws + rowptr_off);
  int*   cursor = (int*)(ws + cursor_off);
  int*   ctot   = (int*)(ws + ctot_off);
  int*   coff   = (int*)(ws + coff_off);
  float* agg    = (float*)(ws + agg_off);
  u32*   pw     = (u32*)(ws + pw_off);
  u32x2* recs   = (u32x2*)(ws + rec_off);

  hipMemsetAsync(cnt, 0, (size_t)N*4, stream);
  prep_kernel<<<64, 256, 0, stream>>>(W1,b1,W2,b2,Wo1,bo1,Wo2,bo2,Wo3,bo3,pw);
  hist_kernel<<<1024, 256, 0, stream>>>(eidx, cnt, E);
  scan1_kernel<<<nchunks, 256, 0, stream>>>(cnt, rowptr, ctot, N);
  scan2_kernel<<<1, 256, 0, stream>>>(ctot, coff, rowptr, nchunks, N, E);
  scan3_kernel<<<nchunks, 256, 0, stream>>>(rowptr, coff, cursor, N);
  scatter_kernel<<<1024, 256, 0, stream>>>(eidx, ep, cursor, recs, E);
  edge_csr_kernel<<<512, 256, 0, stream>>>(x, rowptr, recs, pw, agg, N);
  node_kernel<<<512, 256, 0, stream>>>(x, agg, pw, (float*)d_out, N);
}